// Round 14
// baseline (491.446 us; speedup 1.0000x reference)
//
#include <hip/hip_runtime.h>
#include <stdint.h>

#define B 16
#define D 2
#define NN 100
#define N2 50
#define NA 102
#define H 128
#define HE 64
#define L 3
#define SLOPE 0.2f
#define EPS 1e-5f

#define NAE (NA*NA)          // 10404
#define EN (B*NAE)           // 166464
#define R1 (B*NA)            // 1632
#define R2 (B*N2)            // 800
#define RV (R1 + 2*R2)       // 3232
#define NC 202
#define TI 18                // i-tile rows staged in LDS

// ---- workspace layout (float offsets) ----
#define NODE_PART 1280         // 102*256 -> 27392
#define ACC_FF    27392        // 512 -> 27904
#define OFF_PQR   27904        // 18*384 -> 34816
#define OFF_X0    34816        // raw node embeddings (un-normalized)
#define OFF_V     (OFF_X0 + R1*H)
#define OFF_AB    (OFF_V + 2*RV*H)
#define OFF_XA    (OFF_AB + 2*RV*2*H)      // [ih][g][RV][H]
#define OFF_XL    (OFF_XA + 4*RV*H)        // [ih][g][RV][H]
#define OFF_Z     (OFF_XL + 4*RV*H)

struct KParams {
    const float *x, *dm, *tw, *ead, *ear;
    const float *W0, *W1, *W2, *W3, *W4;
    const float *b0g, *b0b, *b1g, *b1b, *b2g, *b2b, *b3g, *b3b, *b4g, *b4b;
    const float *ffw1, *ffb1, *ffw2, *ffb2, *bng, *bnb;
    const float *Wvla, *Wvlp, *Wvld, *Wga, *Wgp, *Wgd;
    const int *mask_d, *mask_r;
    float *ws, *out;
};

__device__ __forceinline__ void decode_vrow(int ridx, int& b, int& node) {
    if (ridx < R1) { b = ridx / NA; node = ridx % NA; }
    else if (ridx < R1 + R2) { int p = ridx - R1; b = p / N2; node = D + p % N2; }
    else { int p = ridx - R1 - R2; b = p / N2; node = D + N2 + p % N2; }
}
__device__ __forceinline__ void decode_nrow(int vr, int& b, int& node) {
    if (vr < 32) { b = vr >> 1; node = vr & 1; }
    else if (vr < 832) { int p = vr - 32; b = p / N2; node = D + p % N2; }
    else { int p = vr - 832; b = p / N2; node = D + N2 + p % N2; }
}
// reference's scrambled-reshape combine from split (a,l) partial arrays
__device__ __forceinline__ float combined_parts(const float* __restrict__ ws, int g, int b, int node, int k) {
    const float* XA = ws + OFF_XA;
    const float* XL = ws + OFF_XL;
    int r = g*RV + b*NC + node;
    int s = 2*RV;
    float a = XA[r*H + k] + XA[(r + s)*H + k];
    float l = XL[r*H + k] + XL[(r + s)*H + k];
    float v = a / l;
    if (node >= D) {
        int r2 = r + 100;
        float a2 = XA[r2*H + k] + XA[(r2 + s)*H + k];
        float l2 = XL[r2*H + k] + XL[(r2 + s)*H + k];
        v += a2 / l2;
    }
    return v;
}

// ---- launch 1: PQR (18 blocks, self-contained moments scan) | nodeinit (51) | zero (1) ----
__global__ __launch_bounds__(256) void kf_init(KParams p) {
    int u = blockIdx.x, tid = threadIdx.x;
    if (u < 18) {
        int g = u / 9, rem = u % 9, seg = rem / 3, lay = rem % 3;
        __shared__ float sd[256];
        __shared__ float st[192];
        __shared__ float mom[5];
        const float2* ea = (const float2*)(g ? p.ear : p.ead);
        float s0 = 0, s1 = 0, s00 = 0, s11 = 0, s01 = 0;
        for (int idx = tid; idx < EN; idx += 256) {
            float2 v = ea[idx];
            s0 += v.x; s1 += v.y; s00 += v.x*v.x; s11 += v.y*v.y; s01 += v.x*v.y;
        }
        float vals[5] = {s0, s1, s00, s11, s01};
        for (int q = 0; q < 5; q++) {
            sd[tid] = vals[q];
            __syncthreads();
            for (int off = 128; off > 0; off >>= 1) {
                if (tid < off) sd[tid] += sd[tid + off];
                __syncthreads();
            }
            if (tid == 0) mom[q] = sd[0];
            __syncthreads();
        }
        if (tid < 64) {
            const float* W  = g ? p.W4 : p.W3;
            const float* gv = g ? p.b4g : p.b3g;
            const float* bv = g ? p.b4b : p.b3b;
            float Nr = (float)EN;
            float w0 = W[tid], w1 = W[64 + tid];
            float m = (mom[0]*w0 + mom[1]*w1) / Nr;
            float E2 = (mom[2]*w0*w0 + 2.0f*mom[4]*w0*w1 + mom[3]*w1*w1) / Nr;
            float var = E2 - m*m;
            float s = gv[tid] * rsqrtf(var + EPS);
            st[tid] = w0 * s; st[64 + tid] = w1 * s; st[128 + tid] = bv[tid] - m*s;
        }
        __syncthreads();
        if (tid < 128) {
            int h = tid;
            const float* Wg = (seg == 0 ? p.Wga : (seg == 1 ? p.Wgp : p.Wgd)) + lay*320*H;
            float P = 0, Q = 0, Rr = 0;
            for (int cc = 0; cc < HE; cc++) {
                float w = Wg[(2*H + cc)*H + h];
                P += st[cc]*w; Q += st[64 + cc]*w; Rr += st[128 + cc]*w;
            }
            float* o = p.ws + OFF_PQR + ((g*3 + seg)*3 + lay)*384;
            o[h] = P; o[128 + h] = Q; o[256 + h] = Rr;
        }
    } else if (u < 69) {
        int half = tid >> 7, c = tid & 127;
        int vb = (u - 18)*2 + half;
        int seg = (vb < 2) ? 0 : (vb < 52 ? 1 : 2);
        const float* W = seg == 0 ? p.W0 : (seg == 1 ? p.W1 : p.W2);
        int nf = seg == 1 ? 10 : 5;
        float w[10];
        for (int f = 0; f < nf; f++) w[f] = W[f*H + c];
        float* x0 = p.ws + OFF_X0;
        float ls = 0, lss = 0;
        for (int r = 0; r < 16; r++) {
            int vr = vb*16 + r;
            int b, node; decode_nrow(vr, b, node);
            int row = b*NA + node;
            float y = p.x[row*2]*w[0] + p.x[row*2+1]*w[1] + p.dm[row]*w[2]
                    + p.tw[row*2]*w[3] + p.tw[row*2+1]*w[4];
            if (seg == 1) {
                int r2 = row + N2;
                y += p.x[r2*2]*w[5] + p.x[r2*2+1]*w[6] + p.dm[r2]*w[7]
                   + p.tw[r2*2]*w[8] + p.tw[r2*2+1]*w[9];
            }
            x0[row*H + c] = y;
            ls += y; lss += y*y;
        }
        p.ws[NODE_PART + vb*256 + c] = ls;
        p.ws[NODE_PART + vb*256 + 128 + c] = lss;
    } else {
        for (int i = tid; i < 512; i += 256) p.ws[ACC_FF + i] = 0.0f;
    }
}

// ---- fused GEMM (x->V->AB), 8-row tiles; layer 0 applies node-BN on load ----
__global__ __launch_bounds__(256) void kf_gemm(KParams p, int lay) {
    __shared__ float xs[8*H];
    __shared__ float vs[8*H];
    __shared__ float scs[3*128], shs[3*128];
    int g = blockIdx.x / 404, tb = blockIdx.x % 404;
    int rowbase = tb * 8;
    int tid = threadIdx.x;
    float* ws = p.ws;
    if (lay == 0 && tid < 128) {
        int c = tid;
        #pragma unroll
        for (int seg = 0; seg < 3; seg++) {
            int lo = seg == 0 ? 0 : (seg == 1 ? 2 : 52);
            int hi = seg == 0 ? 2 : (seg == 1 ? 52 : 102);
            float s = 0, ss = 0;
            for (int q = lo; q < hi; q++) {
                s  += ws[NODE_PART + q*256 + c];
                ss += ws[NODE_PART + q*256 + 128 + c];
            }
            float cnt = seg == 0 ? 32.0f : 800.0f;
            float m = s / cnt, v = ss / cnt - m*m;
            const float* gp = seg == 0 ? p.b0g : (seg == 1 ? p.b1g : p.b2g);
            const float* bp = seg == 0 ? p.b0b : (seg == 1 ? p.b1b : p.b2b);
            float sc = gp[c] * rsqrtf(v + EPS);
            scs[seg*128 + c] = sc;
            shs[seg*128 + c] = bp[c] - m*sc;
        }
    }
    __syncthreads();
    const float* x0 = ws + OFF_X0;
    for (int e = 0; e < 4; e++) {
        int lin = tid + e*256;
        int r = lin >> 7, k = lin & 127;
        int b, node; decode_vrow(rowbase + r, b, node);
        float val;
        if (lay == 0) {
            int s3 = node < D ? 0 : (node < D + N2 ? 1 : 2);
            val = x0[(b*NA + node)*H + k] * scs[s3*128 + k] + shs[s3*128 + k];
        } else {
            val = combined_parts(ws, g, b, node, k);
        }
        xs[r*H + k] = val;
    }
    __syncthreads();
    int seg = tb < 204 ? 0 : (tb < 304 ? 1 : 2);
    const float* W = (seg == 0 ? p.Wvla : (seg == 1 ? p.Wvlp : p.Wvld)) + lay*H*H;
    int col = tid & 127, half = tid >> 7;
    float acc[4] = {0,0,0,0};
    const float* Wp = W + col;
    #pragma unroll 4
    for (int k4 = 0; k4 < 32; k4++) {
        float w0 = Wp[(4*k4+0)*H], w1 = Wp[(4*k4+1)*H], w2 = Wp[(4*k4+2)*H], w3 = Wp[(4*k4+3)*H];
        #pragma unroll
        for (int rr = 0; rr < 4; rr++) {
            float4 x4 = *(const float4*)&xs[(half + rr*2)*H + 4*k4];
            acc[rr] = fmaf(x4.w, w3, fmaf(x4.z, w2, fmaf(x4.y, w1, fmaf(x4.x, w0, acc[rr]))));
        }
    }
    float* V = ws + OFF_V + g*RV*H;
    #pragma unroll
    for (int rr = 0; rr < 4; rr++) {
        vs[(half + rr*2)*H + col] = acc[rr];
        V[(rowbase + half + rr*2)*H + col] = acc[rr];
    }
    __syncthreads();
    const float* Wg = (seg == 0 ? p.Wga : (seg == 1 ? p.Wgp : p.Wgd)) + lay*320*H;
    const float* wb = Wg + ((tid >> 7) * H) * H + (tid & 127);
    float a2[8];
    #pragma unroll
    for (int rr = 0; rr < 8; rr++) a2[rr] = 0.0f;
    #pragma unroll 4
    for (int k4 = 0; k4 < 32; k4++) {
        float v0 = wb[(4*k4+0)*H], v1 = wb[(4*k4+1)*H], v2 = wb[(4*k4+2)*H], v3 = wb[(4*k4+3)*H];
        #pragma unroll
        for (int rr = 0; rr < 8; rr++) {
            float4 x4 = *(const float4*)&vs[rr*H + 4*k4];
            a2[rr] = fmaf(x4.w, v3, fmaf(x4.z, v2, fmaf(x4.y, v1, fmaf(x4.x, v0, a2[rr]))));
        }
    }
    float* AB = ws + OFF_AB + g*RV*2*H;
    #pragma unroll
    for (int rr = 0; rr < 8; rr++) AB[(rowbase + rr)*256 + tid] = a2[rr];
}

// ---- attention v7: 8 j per block (2 per wave), i-halved blocks, partial (a,l) outputs ----
// grid (8, 216): kx=XCD; y: ih = y&1, y2 = y>>1 in [0,108): ci = y2/27, r = y2%27
__global__ __launch_bounds__(256) void kf_attn(KParams p, int lay) {
    __shared__ float2 Bs[TI*64];
    __shared__ float2 Vs[TI*64];
    __shared__ float2 se[8*52];
    __shared__ int    msk[52];
    int kx = blockIdx.x, y = blockIdx.y;
    int ih = y & 1, y2 = y >> 1;
    int ci = y2 / 27, r = y2 % 27;
    int combo = kx + 8*ci;
    int g = combo >> 4, b = combo & 15;
    int seg, jg, n, o, base;
    if (r < 13)      { seg = 0; jg = r;      n = NA; o = 0;      base = 0; }
    else if (r < 20) { seg = 1; jg = r - 13; n = N2; o = D;      base = R1; }
    else             { seg = 2; jg = r - 20; n = N2; o = D + N2; base = R1 + R2; }
    int j0 = jg * 8;
    int tid = threadIdx.x;
    int c = tid & 63, wv = tid >> 6;
    int jj0 = 2*wv, jj1 = jj0 + 1;
    int ja = j0 + jj0, jb = j0 + jj1;
    bool oka = ja < n, okb = jb < n;
    int nh0 = (n + 1) >> 1;
    int i0 = ih * nh0;
    int cnt = min(nh0, n - i0);

    float* ws = p.ws;
    const float* pqr = ws + OFF_PQR + ((g*3 + seg)*3 + lay)*384;
    float2 Pv = ((const float2*)pqr)[c];
    float2 Qv = ((const float2*)(pqr + 128))[c];
    float2 Rv = ((const float2*)(pqr + 256))[c];
    const float2* ea = (const float2*)(g ? p.ear : p.ead);
    const int* mask = g ? p.mask_r : p.mask_d;
    const float* V  = ws + OFF_V  + g*RV*H   + base*H;
    const float* AB = ws + OFF_AB + g*RV*2*H + base*2*H;

    if (tid < cnt) {
        int i = i0 + tid;
        int ibase = b*NAE + (o + i)*NA + o + j0;
        int bits = 0;
        #pragma unroll
        for (int jj = 0; jj < 8; jj++) {
            int valid = (j0 + jj < n) ? (mask[ibase + jj] != 0) : 0;
            bits |= valid << jj;
            se[jj*52 + tid] = valid ? ea[ibase + jj] : make_float2(0.f, 0.f);
        }
        msk[tid] = bits;
    }

    float A0x = 0.f, A0y = 0.f, A1x = 0.f, A1y = 0.f;
    if (oka) {
        float2 Aj = ((const float2*)&AB[(b*n + ja)*256])[c];
        A0x = Aj.x + Rv.x; A0y = Aj.y + Rv.y;
    }
    if (okb) {
        float2 Aj = ((const float2*)&AB[(b*n + jb)*256])[c];
        A1x = Aj.x + Rv.x; A1y = Aj.y + Rv.y;
    }
    float2 l0 = make_float2(0.f, 0.f), a0 = make_float2(0.f, 0.f);
    float2 l1 = make_float2(0.f, 0.f), a1 = make_float2(0.f, 0.f);

    for (int t0 = 0; t0 < cnt; t0 += TI) {
        int rows = min(TI, cnt - t0);
        __syncthreads();                   // stage visible / prev tile consumed
        for (int idx = tid; idx < rows*64; idx += 256) {
            int ir = idx >> 6, cc = idx & 63;
            int gi = b*n + i0 + t0 + ir;
            Bs[ir*64 + cc] = *(const float2*)&AB[gi*256 + 128 + 2*cc];
            Vs[ir*64 + cc] = *(const float2*)&V[gi*128 + 2*cc];
        }
        __syncthreads();
        for (int ir = 0; ir < rows; ir++) {
            int ii = t0 + ir;
            int bits = (msk[ii] >> jj0) & 3;
            if (!bits) continue;
            float2 Bi = Bs[ir*64 + c];
            float2 Vi = Vs[ir*64 + c];
            if (bits & 1) {
                float2 ev = se[jj0*52 + ii];
                float tx = fmaf(ev.x, Pv.x, fmaf(ev.y, Qv.x, A0x + Bi.x));
                float ty = fmaf(ev.x, Pv.y, fmaf(ev.y, Qv.y, A0y + Bi.y));
                tx = fminf(fmaxf(tx, SLOPE*tx), 80.0f);
                ty = fminf(fmaxf(ty, SLOPE*ty), 80.0f);
                float px = __expf(tx), py = __expf(ty);
                l0.x += px; l0.y += py;
                a0.x = fmaf(px, Vi.x, a0.x); a0.y = fmaf(py, Vi.y, a0.y);
            }
            if (bits & 2) {
                float2 ev = se[jj1*52 + ii];
                float tx = fmaf(ev.x, Pv.x, fmaf(ev.y, Qv.x, A1x + Bi.x));
                float ty = fmaf(ev.x, Pv.y, fmaf(ev.y, Qv.y, A1y + Bi.y));
                tx = fminf(fmaxf(tx, SLOPE*tx), 80.0f);
                ty = fminf(fmaxf(ty, SLOPE*ty), 80.0f);
                float px = __expf(tx), py = __expf(ty);
                l1.x += px; l1.y += py;
                a1.x = fmaf(px, Vi.x, a1.x); a1.y = fmaf(py, Vi.y, a1.y);
            }
        }
    }
    int rowbaseW = (ih*2 + g)*RV + base + b*n;
    if (oka) {
        ((float2*)&ws[OFF_XA + (rowbaseW + ja)*H])[c] = a0;
        ((float2*)&ws[OFF_XL + (rowbaseW + ja)*H])[c] = l0;
    }
    if (okb) {
        ((float2*)&ws[OFF_XA + (rowbaseW + jb)*H])[c] = a1;
        ((float2*)&ws[OFF_XL + (rowbaseW + jb)*H])[c] = l1;
    }
}

// ---- fused feed-forward, 8-row tiles ----
__global__ __launch_bounds__(256) void kf_ff(KParams p) {
    __shared__ float xs[8*H];
    __shared__ float hs[8*H];
    int g = blockIdx.x / 204, tb = blockIdx.x % 204;
    int rowbase = tb * 8;
    int tid = threadIdx.x;
    float* ws = p.ws;
    for (int e = 0; e < 4; e++) {
        int lin = tid + e*256;
        int r = lin >> 7, k = lin & 127;
        int ridx = rowbase + r;
        int b = ridx / NA, node = ridx % NA;
        xs[r*H + k] = combined_parts(ws, g, b, node, k);
    }
    __syncthreads();
    int col = tid & 127, half = tid >> 7;
    float acc[4] = {0,0,0,0};
    const float* W1p = p.ffw1 + col;
    #pragma unroll 4
    for (int k4 = 0; k4 < 32; k4++) {
        float w0 = W1p[(4*k4+0)*H], w1 = W1p[(4*k4+1)*H], w2 = W1p[(4*k4+2)*H], w3 = W1p[(4*k4+3)*H];
        #pragma unroll
        for (int rr = 0; rr < 4; rr++) {
            float4 x4 = *(const float4*)&xs[(half + rr*2)*H + 4*k4];
            acc[rr] = fmaf(x4.w, w3, fmaf(x4.z, w2, fmaf(x4.y, w1, fmaf(x4.x, w0, acc[rr]))));
        }
    }
    float b1 = p.ffb1[col];
    #pragma unroll
    for (int rr = 0; rr < 4; rr++) {
        float hv = acc[rr] + b1;
        hs[(half + rr*2)*H + col] = hv > 0.0f ? hv : 0.0f;
    }
    __syncthreads();
    #pragma unroll
    for (int rr = 0; rr < 4; rr++) acc[rr] = 0.0f;
    const float* W2p = p.ffw2 + col;
    #pragma unroll 4
    for (int k4 = 0; k4 < 32; k4++) {
        float w0 = W2p[(4*k4+0)*H], w1 = W2p[(4*k4+1)*H], w2 = W2p[(4*k4+2)*H], w3 = W2p[(4*k4+3)*H];
        #pragma unroll
        for (int rr = 0; rr < 4; rr++) {
            float4 x4 = *(const float4*)&hs[(half + rr*2)*H + 4*k4];
            acc[rr] = fmaf(x4.w, w3, fmaf(x4.z, w2, fmaf(x4.y, w1, fmaf(x4.x, w0, acc[rr]))));
        }
    }
    float b2 = p.ffb2[col];
    float* Z = ws + OFF_Z + g*R1*H;
    float ls = 0, lss = 0;
    #pragma unroll
    for (int rr = 0; rr < 4; rr++) {
        int row = rowbase + half + rr*2;
        float z = acc[rr] + b2 + xs[(half + rr*2)*H + col];
        Z[row*H + col] = z;
        ls += z; lss += z*z;
    }
    atomicAdd(&ws[ACC_FF + g*256 + col], ls);
    atomicAdd(&ws[ACC_FF + g*256 + 128 + col], lss);
}

// ---- final BN + output (grid-stride) ----
__global__ __launch_bounds__(256) void kf_f3(KParams p) {
    for (int e = blockIdx.x*256 + threadIdx.x; e < 2*R1*H; e += 408*256) {
        int g = e / (R1*H);
        int c = e & 127;
        float m = p.ws[ACC_FF + g*256 + c] / 1632.0f;
        float v = p.ws[ACC_FF + g*256 + 128 + c] / 1632.0f - m*m;
        float sc = p.bng[c] * rsqrtf(v + EPS);
        float sh = p.bnb[c] - m*sc;
        p.out[e] = p.ws[OFF_Z + e] * sc + sh;
    }
}

extern "C" void kernel_launch(void* const* d_in, const int* in_sizes, int n_in,
                              void* d_out, int out_size, void* d_ws, size_t ws_size,
                              hipStream_t stream) {
    KParams p;
    p.x    = (const float*)d_in[0];
    p.dm   = (const float*)d_in[1];
    p.tw   = (const float*)d_in[2];
    p.ead  = (const float*)d_in[3];
    p.ear  = (const float*)d_in[4];
    p.W0   = (const float*)d_in[5];
    p.W1   = (const float*)d_in[6];
    p.W2   = (const float*)d_in[7];
    p.W3   = (const float*)d_in[8];
    p.W4   = (const float*)d_in[9];
    p.b0g  = (const float*)d_in[10];
    p.b0b  = (const float*)d_in[11];
    p.b1g  = (const float*)d_in[12];
    p.b1b  = (const float*)d_in[13];
    p.b2g  = (const float*)d_in[14];
    p.b2b  = (const float*)d_in[15];
    p.b3g  = (const float*)d_in[16];
    p.b3b  = (const float*)d_in[17];
    p.b4g  = (const float*)d_in[18];
    p.b4b  = (const float*)d_in[19];
    p.ffw1 = (const float*)d_in[20];
    p.ffb1 = (const float*)d_in[21];
    p.ffw2 = (const float*)d_in[22];
    p.ffb2 = (const float*)d_in[23];
    p.bng  = (const float*)d_in[24];
    p.bnb  = (const float*)d_in[25];
    p.Wvla = (const float*)d_in[26];
    p.Wvlp = (const float*)d_in[27];
    p.Wvld = (const float*)d_in[28];
    p.Wga  = (const float*)d_in[29];
    p.Wgp  = (const float*)d_in[30];
    p.Wgd  = (const float*)d_in[31];
    p.mask_d = (const int*)d_in[33];
    p.mask_r = (const int*)d_in[34];
    p.ws  = (float*)d_ws;
    p.out = (float*)d_out;

    kf_init<<<70, 256, 0, stream>>>(p);
    for (int lay = 0; lay < L; lay++) {
        kf_gemm<<<808, 256, 0, stream>>>(p, lay);
        kf_attn<<<dim3(8, 216), 256, 0, stream>>>(p, lay);
    }
    kf_ff<<<408, 256, 0, stream>>>(p);
    kf_f3<<<408, 256, 0, stream>>>(p);
}

// Round 15
// 329.969 us; speedup vs baseline: 1.4894x; 1.4894x over previous
//
#include <hip/hip_runtime.h>
#include <stdint.h>

#define B 16
#define D 2
#define NN 100
#define N2 50
#define NA 102
#define H 128
#define HE 64
#define L 3
#define SLOPE 0.2f
#define EPS 1e-5f

#define NAE (NA*NA)          // 10404
#define EN (B*NAE)           // 166464
#define R1 (B*NA)            // 1632
#define R2 (B*N2)            // 800
#define RV (R1 + 2*R2)       // 3232
#define NC 202
#define TI 18                // i-tile rows staged in LDS

// ---- workspace layout (float offsets) ----
#define MOM_PART  0            // 256*5
#define NODE_PART 1280         // 102*256 -> 27392
#define ACC_FF    27392        // 512 -> 27904
#define OFF_PQR   27904        // 18*384 -> 34816
#define OFF_X0    34816        // raw node embeddings (un-normalized)
#define OFF_V     (OFF_X0 + R1*H)
#define OFF_AB    (OFF_V + 2*RV*H)
#define OFF_XA    (OFF_AB + 2*RV*2*H)      // [ih][g][RV][H]
#define OFF_XL    (OFF_XA + 4*RV*H)        // [ih][g][RV][H]
#define OFF_Z     (OFF_XL + 4*RV*H)

struct KParams {
    const float *x, *dm, *tw, *ead, *ear;
    const float *W0, *W1, *W2, *W3, *W4;
    const float *b0g, *b0b, *b1g, *b1b, *b2g, *b2b, *b3g, *b3b, *b4g, *b4b;
    const float *ffw1, *ffb1, *ffw2, *ffb2, *bng, *bnb;
    const float *Wvla, *Wvlp, *Wvld, *Wga, *Wgp, *Wgd;
    const int *mask_d, *mask_r;
    float *ws, *out;
};

__device__ __forceinline__ void decode_vrow(int ridx, int& b, int& node) {
    if (ridx < R1) { b = ridx / NA; node = ridx % NA; }
    else if (ridx < R1 + R2) { int p = ridx - R1; b = p / N2; node = D + p % N2; }
    else { int p = ridx - R1 - R2; b = p / N2; node = D + N2 + p % N2; }
}
__device__ __forceinline__ void decode_nrow(int vr, int& b, int& node) {
    if (vr < 32) { b = vr >> 1; node = vr & 1; }
    else if (vr < 832) { int p = vr - 32; b = p / N2; node = D + p % N2; }
    else { int p = vr - 832; b = p / N2; node = D + N2 + p % N2; }
}
// reference's scrambled-reshape combine from split (a,l) partial arrays — float4-wide
__device__ __forceinline__ float4 combined_parts4(const float* __restrict__ ws, int g, int b, int node, int kq) {
    const float* XA = ws + OFF_XA;
    const float* XL = ws + OFF_XL;
    int r = g*RV + b*NC + node;
    int s = 2*RV;
    float4 a0 = *(const float4*)&XA[r*H + 4*kq];
    float4 a1 = *(const float4*)&XA[(r + s)*H + 4*kq];
    float4 l0 = *(const float4*)&XL[r*H + 4*kq];
    float4 l1 = *(const float4*)&XL[(r + s)*H + 4*kq];
    float4 v;
    v.x = (a0.x + a1.x) / (l0.x + l1.x);
    v.y = (a0.y + a1.y) / (l0.y + l1.y);
    v.z = (a0.z + a1.z) / (l0.z + l1.z);
    v.w = (a0.w + a1.w) / (l0.w + l1.w);
    if (node >= D) {
        int r2 = r + 100;
        float4 c0 = *(const float4*)&XA[r2*H + 4*kq];
        float4 c1 = *(const float4*)&XA[(r2 + s)*H + 4*kq];
        float4 d0 = *(const float4*)&XL[r2*H + 4*kq];
        float4 d1 = *(const float4*)&XL[(r2 + s)*H + 4*kq];
        v.x += (c0.x + c1.x) / (d0.x + d1.x);
        v.y += (c0.y + c1.y) / (d0.y + d1.y);
        v.z += (c0.z + c1.z) / (d0.z + d1.z);
        v.w += (c0.w + c1.w) / (d0.w + d1.w);
    }
    return v;
}

// ---- launch 1: moments partials (256) | nodeinit partials (51) | zero ACC_FF (1) ----
__global__ __launch_bounds__(256) void kf_A(KParams p) {
    __shared__ float sd[256];
    int u = blockIdx.x, tid = threadIdx.x;
    if (u < 256) {
        int g = u >> 7, bb = u & 127;
        const float2* ea = (const float2*)(g ? p.ear : p.ead);
        float s0 = 0, s1 = 0, s00 = 0, s11 = 0, s01 = 0;
        for (int idx = bb*256 + tid; idx < EN; idx += 128*256) {
            float2 v = ea[idx];
            s0 += v.x; s1 += v.y; s00 += v.x*v.x; s11 += v.y*v.y; s01 += v.x*v.y;
        }
        float vals[5] = {s0, s1, s00, s11, s01};
        for (int q = 0; q < 5; q++) {
            sd[tid] = vals[q];
            __syncthreads();
            for (int off = 128; off > 0; off >>= 1) {
                if (tid < off) sd[tid] += sd[tid + off];
                __syncthreads();
            }
            if (tid == 0) p.ws[MOM_PART + (g*128 + bb)*5 + q] = sd[0];
            __syncthreads();
        }
    } else if (u < 307) {
        int half = tid >> 7, c = tid & 127;
        int vb = (u - 256)*2 + half;
        int seg = (vb < 2) ? 0 : (vb < 52 ? 1 : 2);
        const float* W = seg == 0 ? p.W0 : (seg == 1 ? p.W1 : p.W2);
        int nf = seg == 1 ? 10 : 5;
        float w[10];
        for (int f = 0; f < nf; f++) w[f] = W[f*H + c];
        float* x0 = p.ws + OFF_X0;
        float ls = 0, lss = 0;
        for (int r = 0; r < 16; r++) {
            int vr = vb*16 + r;
            int b, node; decode_nrow(vr, b, node);
            int row = b*NA + node;
            float y = p.x[row*2]*w[0] + p.x[row*2+1]*w[1] + p.dm[row]*w[2]
                    + p.tw[row*2]*w[3] + p.tw[row*2+1]*w[4];
            if (seg == 1) {
                int r2 = row + N2;
                y += p.x[r2*2]*w[5] + p.x[r2*2+1]*w[6] + p.dm[r2]*w[7]
                   + p.tw[r2*2]*w[8] + p.tw[r2*2+1]*w[9];
            }
            x0[row*H + c] = y;
            ls += y; lss += y*y;
        }
        p.ws[NODE_PART + vb*256 + c] = ls;
        p.ws[NODE_PART + vb*256 + 128 + c] = lss;
    } else {
        for (int i = tid; i < 512; i += 256) p.ws[ACC_FF + i] = 0.0f;
    }
}

// ---- launch 2: reduce moments, fold edge BN + we into P/Q/R ----
__global__ __launch_bounds__(128) void kf_pqr(KParams p) {
    int u = blockIdx.x;            // 18
    int g = u / 9, rem = u % 9, seg = rem / 3, lay = rem % 3;
    __shared__ float st[192];
    __shared__ float momsh[5];
    int t = threadIdx.x;
    if (t < 5) {
        float s = 0;
        for (int q = 0; q < 128; q++) s += p.ws[MOM_PART + (g*128 + q)*5 + t];
        momsh[t] = s;
    }
    __syncthreads();
    if (t < 64) {
        const float* W  = g ? p.W4 : p.W3;
        const float* gv = g ? p.b4g : p.b3g;
        const float* bv = g ? p.b4b : p.b3b;
        float Nr = (float)EN;
        float S0 = momsh[0], S1 = momsh[1], S00 = momsh[2], S11 = momsh[3], S01 = momsh[4];
        float w0 = W[t], w1 = W[64 + t];
        float m = (S0*w0 + S1*w1) / Nr;
        float E2 = (S00*w0*w0 + 2.0f*S01*w0*w1 + S11*w1*w1) / Nr;
        float var = E2 - m*m;
        float s = gv[t] * rsqrtf(var + EPS);
        st[t] = w0 * s; st[64 + t] = w1 * s; st[128 + t] = bv[t] - m*s;
    }
    __syncthreads();
    int h = t;
    const float* Wg = (seg == 0 ? p.Wga : (seg == 1 ? p.Wgp : p.Wgd)) + lay*320*H;
    float P = 0, Q = 0, Rr = 0;
    for (int cc = 0; cc < HE; cc++) {
        float w = Wg[(2*H + cc)*H + h];
        P += st[cc]*w; Q += st[64 + cc]*w; Rr += st[128 + cc]*w;
    }
    float* o = p.ws + OFF_PQR + ((g*3 + seg)*3 + lay)*384;
    o[h] = P; o[128 + h] = Q; o[256 + h] = Rr;
}

// ---- fused GEMM (x->V->AB), 8-row tiles; float4 stage; layer 0 applies node-BN ----
__global__ __launch_bounds__(256) void kf_gemm(KParams p, int lay) {
    __shared__ float xs[8*H];
    __shared__ float vs[8*H];
    __shared__ float scs[3*128], shs[3*128];
    int g = blockIdx.x / 404, tb = blockIdx.x % 404;
    int rowbase = tb * 8;
    int tid = threadIdx.x;
    float* ws = p.ws;
    if (lay == 0 && tid < 128) {
        int c = tid;
        #pragma unroll
        for (int seg = 0; seg < 3; seg++) {
            int lo = seg == 0 ? 0 : (seg == 1 ? 2 : 52);
            int hi = seg == 0 ? 2 : (seg == 1 ? 52 : 102);
            float s = 0, ss = 0;
            for (int q = lo; q < hi; q++) {
                s  += ws[NODE_PART + q*256 + c];
                ss += ws[NODE_PART + q*256 + 128 + c];
            }
            float cnt = seg == 0 ? 32.0f : 800.0f;
            float m = s / cnt, v = ss / cnt - m*m;
            const float* gp = seg == 0 ? p.b0g : (seg == 1 ? p.b1g : p.b2g);
            const float* bp = seg == 0 ? p.b0b : (seg == 1 ? p.b1b : p.b2b);
            float sc = gp[c] * rsqrtf(v + EPS);
            scs[seg*128 + c] = sc;
            shs[seg*128 + c] = bp[c] - m*sc;
        }
    }
    __syncthreads();
    // stage: 8 rows x 32 k-quads = 256 slots, one per thread
    {
        int r = tid >> 5, kq = tid & 31;
        int b, node; decode_vrow(rowbase + r, b, node);
        float4 val;
        if (lay == 0) {
            const float* x0 = ws + OFF_X0;
            int s3 = node < D ? 0 : (node < D + N2 ? 1 : 2);
            float4 xv = *(const float4*)&x0[(b*NA + node)*H + 4*kq];
            float4 sc = *(const float4*)&scs[s3*128 + 4*kq];
            float4 sh = *(const float4*)&shs[s3*128 + 4*kq];
            val.x = xv.x*sc.x + sh.x; val.y = xv.y*sc.y + sh.y;
            val.z = xv.z*sc.z + sh.z; val.w = xv.w*sc.w + sh.w;
        } else {
            val = combined_parts4(ws, g, b, node, kq);
        }
        *(float4*)&xs[r*H + 4*kq] = val;
    }
    __syncthreads();
    int seg = tb < 204 ? 0 : (tb < 304 ? 1 : 2);
    const float* W = (seg == 0 ? p.Wvla : (seg == 1 ? p.Wvlp : p.Wvld)) + lay*H*H;
    int col = tid & 127, half = tid >> 7;
    float acc[4] = {0,0,0,0};
    const float* Wp = W + col;
    #pragma unroll 4
    for (int k4 = 0; k4 < 32; k4++) {
        float w0 = Wp[(4*k4+0)*H], w1 = Wp[(4*k4+1)*H], w2 = Wp[(4*k4+2)*H], w3 = Wp[(4*k4+3)*H];
        #pragma unroll
        for (int rr = 0; rr < 4; rr++) {
            float4 x4 = *(const float4*)&xs[(half + rr*2)*H + 4*k4];
            acc[rr] = fmaf(x4.w, w3, fmaf(x4.z, w2, fmaf(x4.y, w1, fmaf(x4.x, w0, acc[rr]))));
        }
    }
    float* V = ws + OFF_V + g*RV*H;
    #pragma unroll
    for (int rr = 0; rr < 4; rr++) {
        vs[(half + rr*2)*H + col] = acc[rr];
        V[(rowbase + half + rr*2)*H + col] = acc[rr];
    }
    __syncthreads();
    const float* Wg = (seg == 0 ? p.Wga : (seg == 1 ? p.Wgp : p.Wgd)) + lay*320*H;
    const float* wb = Wg + ((tid >> 7) * H) * H + (tid & 127);
    float a2[8];
    #pragma unroll
    for (int rr = 0; rr < 8; rr++) a2[rr] = 0.0f;
    #pragma unroll 4
    for (int k4 = 0; k4 < 32; k4++) {
        float v0 = wb[(4*k4+0)*H], v1 = wb[(4*k4+1)*H], v2 = wb[(4*k4+2)*H], v3 = wb[(4*k4+3)*H];
        #pragma unroll
        for (int rr = 0; rr < 8; rr++) {
            float4 x4 = *(const float4*)&vs[rr*H + 4*k4];
            a2[rr] = fmaf(x4.w, v3, fmaf(x4.z, v2, fmaf(x4.y, v1, fmaf(x4.x, v0, a2[rr]))));
        }
    }
    float* AB = ws + OFF_AB + g*RV*2*H;
    #pragma unroll
    for (int rr = 0; rr < 8; rr++) AB[(rowbase + rr)*256 + tid] = a2[rr];
}

// ---- attention v7: 8 j per block (2 per wave), i-halved blocks, partial (a,l) outputs ----
// grid (8, 216): kx=XCD; y: ih = y&1, y2 = y>>1 in [0,108): ci = y2/27, r = y2%27
__global__ __launch_bounds__(256) void kf_attn(KParams p, int lay) {
    __shared__ float2 Bs[TI*64];
    __shared__ float2 Vs[TI*64];
    __shared__ float2 se[8*52];
    __shared__ int    msk[52];
    int kx = blockIdx.x, y = blockIdx.y;
    int ih = y & 1, y2 = y >> 1;
    int ci = y2 / 27, r = y2 % 27;
    int combo = kx + 8*ci;
    int g = combo >> 4, b = combo & 15;
    int seg, jg, n, o, base;
    if (r < 13)      { seg = 0; jg = r;      n = NA; o = 0;      base = 0; }
    else if (r < 20) { seg = 1; jg = r - 13; n = N2; o = D;      base = R1; }
    else             { seg = 2; jg = r - 20; n = N2; o = D + N2; base = R1 + R2; }
    int j0 = jg * 8;
    int tid = threadIdx.x;
    int c = tid & 63, wv = tid >> 6;
    int jj0 = 2*wv, jj1 = jj0 + 1;
    int ja = j0 + jj0, jb = j0 + jj1;
    bool oka = ja < n, okb = jb < n;
    int nh0 = (n + 1) >> 1;
    int i0 = ih * nh0;
    int cnt = min(nh0, n - i0);

    float* ws = p.ws;
    const float* pqr = ws + OFF_PQR + ((g*3 + seg)*3 + lay)*384;
    float2 Pv = ((const float2*)pqr)[c];
    float2 Qv = ((const float2*)(pqr + 128))[c];
    float2 Rv = ((const float2*)(pqr + 256))[c];
    const float2* ea = (const float2*)(g ? p.ear : p.ead);
    const int* mask = g ? p.mask_r : p.mask_d;
    const float* V  = ws + OFF_V  + g*RV*H   + base*H;
    const float* AB = ws + OFF_AB + g*RV*2*H + base*2*H;

    if (tid < cnt) {
        int i = i0 + tid;
        int ibase = b*NAE + (o + i)*NA + o + j0;
        int bits = 0;
        #pragma unroll
        for (int jj = 0; jj < 8; jj++) {
            int valid = (j0 + jj < n) ? (mask[ibase + jj] != 0) : 0;
            bits |= valid << jj;
            se[jj*52 + tid] = valid ? ea[ibase + jj] : make_float2(0.f, 0.f);
        }
        msk[tid] = bits;
    }

    float A0x = 0.f, A0y = 0.f, A1x = 0.f, A1y = 0.f;
    if (oka) {
        float2 Aj = ((const float2*)&AB[(b*n + ja)*256])[c];
        A0x = Aj.x + Rv.x; A0y = Aj.y + Rv.y;
    }
    if (okb) {
        float2 Aj = ((const float2*)&AB[(b*n + jb)*256])[c];
        A1x = Aj.x + Rv.x; A1y = Aj.y + Rv.y;
    }
    float2 l0 = make_float2(0.f, 0.f), a0 = make_float2(0.f, 0.f);
    float2 l1 = make_float2(0.f, 0.f), a1 = make_float2(0.f, 0.f);

    for (int t0 = 0; t0 < cnt; t0 += TI) {
        int rows = min(TI, cnt - t0);
        __syncthreads();                   // stage visible / prev tile consumed
        for (int idx = tid; idx < rows*64; idx += 256) {
            int ir = idx >> 6, cc = idx & 63;
            int gi = b*n + i0 + t0 + ir;
            Bs[ir*64 + cc] = *(const float2*)&AB[gi*256 + 128 + 2*cc];
            Vs[ir*64 + cc] = *(const float2*)&V[gi*128 + 2*cc];
        }
        __syncthreads();
        for (int ir = 0; ir < rows; ir++) {
            int ii = t0 + ir;
            int bits = (msk[ii] >> jj0) & 3;
            if (!bits) continue;
            float2 Bi = Bs[ir*64 + c];
            float2 Vi = Vs[ir*64 + c];
            if (bits & 1) {
                float2 ev = se[jj0*52 + ii];
                float tx = fmaf(ev.x, Pv.x, fmaf(ev.y, Qv.x, A0x + Bi.x));
                float ty = fmaf(ev.x, Pv.y, fmaf(ev.y, Qv.y, A0y + Bi.y));
                tx = fminf(fmaxf(tx, SLOPE*tx), 80.0f);
                ty = fminf(fmaxf(ty, SLOPE*ty), 80.0f);
                float px = __expf(tx), py = __expf(ty);
                l0.x += px; l0.y += py;
                a0.x = fmaf(px, Vi.x, a0.x); a0.y = fmaf(py, Vi.y, a0.y);
            }
            if (bits & 2) {
                float2 ev = se[jj1*52 + ii];
                float tx = fmaf(ev.x, Pv.x, fmaf(ev.y, Qv.x, A1x + Bi.x));
                float ty = fmaf(ev.x, Pv.y, fmaf(ev.y, Qv.y, A1y + Bi.y));
                tx = fminf(fmaxf(tx, SLOPE*tx), 80.0f);
                ty = fminf(fmaxf(ty, SLOPE*ty), 80.0f);
                float px = __expf(tx), py = __expf(ty);
                l1.x += px; l1.y += py;
                a1.x = fmaf(px, Vi.x, a1.x); a1.y = fmaf(py, Vi.y, a1.y);
            }
        }
    }
    int rowbaseW = (ih*2 + g)*RV + base + b*n;
    if (oka) {
        ((float2*)&ws[OFF_XA + (rowbaseW + ja)*H])[c] = a0;
        ((float2*)&ws[OFF_XL + (rowbaseW + ja)*H])[c] = l0;
    }
    if (okb) {
        ((float2*)&ws[OFF_XA + (rowbaseW + jb)*H])[c] = a1;
        ((float2*)&ws[OFF_XL + (rowbaseW + jb)*H])[c] = l1;
    }
}

// ---- fused feed-forward, 8-row tiles; float4 stage ----
__global__ __launch_bounds__(256) void kf_ff(KParams p) {
    __shared__ float xs[8*H];
    __shared__ float hs[8*H];
    int g = blockIdx.x / 204, tb = blockIdx.x % 204;
    int rowbase = tb * 8;
    int tid = threadIdx.x;
    float* ws = p.ws;
    {
        int r = tid >> 5, kq = tid & 31;
        int ridx = rowbase + r;
        int b = ridx / NA, node = ridx % NA;
        float4 val = combined_parts4(ws, g, b, node, kq);
        *(float4*)&xs[r*H + 4*kq] = val;
    }
    __syncthreads();
    int col = tid & 127, half = tid >> 7;
    float acc[4] = {0,0,0,0};
    const float* W1p = p.ffw1 + col;
    #pragma unroll 4
    for (int k4 = 0; k4 < 32; k4++) {
        float w0 = W1p[(4*k4+0)*H], w1 = W1p[(4*k4+1)*H], w2 = W1p[(4*k4+2)*H], w3 = W1p[(4*k4+3)*H];
        #pragma unroll
        for (int rr = 0; rr < 4; rr++) {
            float4 x4 = *(const float4*)&xs[(half + rr*2)*H + 4*k4];
            acc[rr] = fmaf(x4.w, w3, fmaf(x4.z, w2, fmaf(x4.y, w1, fmaf(x4.x, w0, acc[rr]))));
        }
    }
    float b1 = p.ffb1[col];
    #pragma unroll
    for (int rr = 0; rr < 4; rr++) {
        float hv = acc[rr] + b1;
        hs[(half + rr*2)*H + col] = hv > 0.0f ? hv : 0.0f;
    }
    __syncthreads();
    #pragma unroll
    for (int rr = 0; rr < 4; rr++) acc[rr] = 0.0f;
    const float* W2p = p.ffw2 + col;
    #pragma unroll 4
    for (int k4 = 0; k4 < 32; k4++) {
        float w0 = W2p[(4*k4+0)*H], w1 = W2p[(4*k4+1)*H], w2 = W2p[(4*k4+2)*H], w3 = W2p[(4*k4+3)*H];
        #pragma unroll
        for (int rr = 0; rr < 4; rr++) {
            float4 x4 = *(const float4*)&hs[(half + rr*2)*H + 4*k4];
            acc[rr] = fmaf(x4.w, w3, fmaf(x4.z, w2, fmaf(x4.y, w1, fmaf(x4.x, w0, acc[rr]))));
        }
    }
    float b2 = p.ffb2[col];
    float* Z = ws + OFF_Z + g*R1*H;
    float ls = 0, lss = 0;
    #pragma unroll
    for (int rr = 0; rr < 4; rr++) {
        int row = rowbase + half + rr*2;
        float z = acc[rr] + b2 + xs[(half + rr*2)*H + col];
        Z[row*H + col] = z;
        ls += z; lss += z*z;
    }
    atomicAdd(&ws[ACC_FF + g*256 + col], ls);
    atomicAdd(&ws[ACC_FF + g*256 + 128 + col], lss);
}

// ---- final BN + output (grid-stride) ----
__global__ __launch_bounds__(256) void kf_f3(KParams p) {
    for (int e = blockIdx.x*256 + threadIdx.x; e < 2*R1*H; e += 408*256) {
        int g = e / (R1*H);
        int c = e & 127;
        float m = p.ws[ACC_FF + g*256 + c] / 1632.0f;
        float v = p.ws[ACC_FF + g*256 + 128 + c] / 1632.0f - m*m;
        float sc = p.bng[c] * rsqrtf(v + EPS);
        float sh = p.bnb[c] - m*sc;
        p.out[e] = p.ws[OFF_Z + e] * sc + sh;
    }
}

extern "C" void kernel_launch(void* const* d_in, const int* in_sizes, int n_in,
                              void* d_out, int out_size, void* d_ws, size_t ws_size,
                              hipStream_t stream) {
    KParams p;
    p.x    = (const float*)d_in[0];
    p.dm   = (const float*)d_in[1];
    p.tw   = (const float*)d_in[2];
    p.ead  = (const float*)d_in[3];
    p.ear  = (const float*)d_in[4];
    p.W0   = (const float*)d_in[5];
    p.W1   = (const float*)d_in[6];
    p.W2   = (const float*)d_in[7];
    p.W3   = (const float*)d_in[8];
    p.W4   = (const float*)d_in[9];
    p.b0g  = (const float*)d_in[10];
    p.b0b  = (const float*)d_in[11];
    p.b1g  = (const float*)d_in[12];
    p.b1b  = (const float*)d_in[13];
    p.b2g  = (const float*)d_in[14];
    p.b2b  = (const float*)d_in[15];
    p.b3g  = (const float*)d_in[16];
    p.b3b  = (const float*)d_in[17];
    p.b4g  = (const float*)d_in[18];
    p.b4b  = (const float*)d_in[19];
    p.ffw1 = (const float*)d_in[20];
    p.ffb1 = (const float*)d_in[21];
    p.ffw2 = (const float*)d_in[22];
    p.ffb2 = (const float*)d_in[23];
    p.bng  = (const float*)d_in[24];
    p.bnb  = (const float*)d_in[25];
    p.Wvla = (const float*)d_in[26];
    p.Wvlp = (const float*)d_in[27];
    p.Wvld = (const float*)d_in[28];
    p.Wga  = (const float*)d_in[29];
    p.Wgp  = (const float*)d_in[30];
    p.Wgd  = (const float*)d_in[31];
    p.mask_d = (const int*)d_in[33];
    p.mask_r = (const int*)d_in[34];
    p.ws  = (float*)d_ws;
    p.out = (float*)d_out;

    kf_A  <<<308, 256, 0, stream>>>(p);
    kf_pqr<<<18, 128, 0, stream>>>(p);
    for (int lay = 0; lay < L; lay++) {
        kf_gemm<<<808, 256, 0, stream>>>(p, lay);
        kf_attn<<<dim3(8, 216), 256, 0, stream>>>(p, lay);
    }
    kf_ff<<<408, 256, 0, stream>>>(p);
    kf_f3<<<408, 256, 0, stream>>>(p);
}

// Round 16
// 305.367 us; speedup vs baseline: 1.6094x; 1.0806x over previous
//
#include <hip/hip_runtime.h>
#include <stdint.h>

#define B 16
#define D 2
#define NN 100
#define N2 50
#define NA 102
#define H 128
#define HE 64
#define L 3
#define SLOPE 0.2f
#define EPS 1e-5f

#define NAE (NA*NA)          // 10404
#define EN (B*NAE)           // 166464
#define R1 (B*NA)            // 1632
#define R2 (B*N2)            // 800
#define RV (R1 + 2*R2)       // 3232
#define NC 202
#define TI 18                // i-tile rows staged in LDS

// ---- workspace layout (float offsets) ----
#define MOM_PART  0            // 256*5
#define NODE_PART 1280         // 102*256 -> 27392
#define ACC_FF    27392        // 512 -> 27904
#define OFF_PQR   27904        // 18*384 -> 34816
#define OFF_X0    34816        // raw node embeddings (un-normalized)
#define OFF_V     (OFF_X0 + R1*H)
#define OFF_AB    (OFF_V + 2*RV*H)
#define OFF_XA    (OFF_AB + 2*RV*2*H)      // [ih][g][RV][H]
#define OFF_XL    (OFF_XA + 4*RV*H)        // [ih][g][RV][H]
#define OFF_Z     (OFF_XL + 4*RV*H)

struct KParams {
    const float *x, *dm, *tw, *ead, *ear;
    const float *W0, *W1, *W2, *W3, *W4;
    const float *b0g, *b0b, *b1g, *b1b, *b2g, *b2b, *b3g, *b3b, *b4g, *b4b;
    const float *ffw1, *ffb1, *ffw2, *ffb2, *bng, *bnb;
    const float *Wvla, *Wvlp, *Wvld, *Wga, *Wgp, *Wgd;
    const int *mask_d, *mask_r;
    float *ws, *out;
};

__device__ __forceinline__ void decode_vrow(int ridx, int& b, int& node) {
    if (ridx < R1) { b = ridx / NA; node = ridx % NA; }
    else if (ridx < R1 + R2) { int p = ridx - R1; b = p / N2; node = D + p % N2; }
    else { int p = ridx - R1 - R2; b = p / N2; node = D + N2 + p % N2; }
}
__device__ __forceinline__ void decode_nrow(int vr, int& b, int& node) {
    if (vr < 32) { b = vr >> 1; node = vr & 1; }
    else if (vr < 832) { int p = vr - 32; b = p / N2; node = D + p % N2; }
    else { int p = vr - 832; b = p / N2; node = D + N2 + p % N2; }
}
// reference's scrambled-reshape combine from split (a,l) partial arrays — float4-wide
__device__ __forceinline__ float4 combined_parts4(const float* __restrict__ ws, int g, int b, int node, int kq) {
    const float* XA = ws + OFF_XA;
    const float* XL = ws + OFF_XL;
    int r = g*RV + b*NC + node;
    int s = 2*RV;
    float4 a0 = *(const float4*)&XA[r*H + 4*kq];
    float4 a1 = *(const float4*)&XA[(r + s)*H + 4*kq];
    float4 l0 = *(const float4*)&XL[r*H + 4*kq];
    float4 l1 = *(const float4*)&XL[(r + s)*H + 4*kq];
    float4 v;
    v.x = (a0.x + a1.x) / (l0.x + l1.x);
    v.y = (a0.y + a1.y) / (l0.y + l1.y);
    v.z = (a0.z + a1.z) / (l0.z + l1.z);
    v.w = (a0.w + a1.w) / (l0.w + l1.w);
    if (node >= D) {
        int r2 = r + 100;
        float4 c0 = *(const float4*)&XA[r2*H + 4*kq];
        float4 c1 = *(const float4*)&XA[(r2 + s)*H + 4*kq];
        float4 d0 = *(const float4*)&XL[r2*H + 4*kq];
        float4 d1 = *(const float4*)&XL[(r2 + s)*H + 4*kq];
        v.x += (c0.x + c1.x) / (d0.x + d1.x);
        v.y += (c0.y + c1.y) / (d0.y + d1.y);
        v.z += (c0.z + c1.z) / (d0.z + d1.z);
        v.w += (c0.w + c1.w) / (d0.w + d1.w);
    }
    return v;
}

// ---- launch 1: moments partials (256) | nodeinit partials (51) | zero ACC_FF (1) ----
__global__ __launch_bounds__(256) void kf_A(KParams p) {
    __shared__ float sd[256];
    int u = blockIdx.x, tid = threadIdx.x;
    if (u < 256) {
        int g = u >> 7, bb = u & 127;
        const float2* ea = (const float2*)(g ? p.ear : p.ead);
        float s0 = 0, s1 = 0, s00 = 0, s11 = 0, s01 = 0;
        for (int idx = bb*256 + tid; idx < EN; idx += 128*256) {
            float2 v = ea[idx];
            s0 += v.x; s1 += v.y; s00 += v.x*v.x; s11 += v.y*v.y; s01 += v.x*v.y;
        }
        float vals[5] = {s0, s1, s00, s11, s01};
        for (int q = 0; q < 5; q++) {
            sd[tid] = vals[q];
            __syncthreads();
            for (int off = 128; off > 0; off >>= 1) {
                if (tid < off) sd[tid] += sd[tid + off];
                __syncthreads();
            }
            if (tid == 0) p.ws[MOM_PART + (g*128 + bb)*5 + q] = sd[0];
            __syncthreads();
        }
    } else if (u < 307) {
        int half = tid >> 7, c = tid & 127;
        int vb = (u - 256)*2 + half;
        int seg = (vb < 2) ? 0 : (vb < 52 ? 1 : 2);
        const float* W = seg == 0 ? p.W0 : (seg == 1 ? p.W1 : p.W2);
        int nf = seg == 1 ? 10 : 5;
        float w[10];
        for (int f = 0; f < nf; f++) w[f] = W[f*H + c];
        float* x0 = p.ws + OFF_X0;
        float ls = 0, lss = 0;
        for (int r = 0; r < 16; r++) {
            int vr = vb*16 + r;
            int b, node; decode_nrow(vr, b, node);
            int row = b*NA + node;
            float y = p.x[row*2]*w[0] + p.x[row*2+1]*w[1] + p.dm[row]*w[2]
                    + p.tw[row*2]*w[3] + p.tw[row*2+1]*w[4];
            if (seg == 1) {
                int r2 = row + N2;
                y += p.x[r2*2]*w[5] + p.x[r2*2+1]*w[6] + p.dm[r2]*w[7]
                   + p.tw[r2*2]*w[8] + p.tw[r2*2+1]*w[9];
            }
            x0[row*H + c] = y;
            ls += y; lss += y*y;
        }
        p.ws[NODE_PART + vb*256 + c] = ls;
        p.ws[NODE_PART + vb*256 + 128 + c] = lss;
    } else {
        for (int i = tid; i < 512; i += 256) p.ws[ACC_FF + i] = 0.0f;
    }
}

// ---- pqr body (runs as tail blocks of kf_gemm lay 0) ----
__device__ void pqr_body(int u, int t, const KParams& p) {
    int g = u / 9, rem = u % 9, seg = rem / 3, lay = rem % 3;
    __shared__ float st[192];
    __shared__ float momsh[5];
    if (t < 5) {
        float s = 0;
        for (int q = 0; q < 128; q++) s += p.ws[MOM_PART + (g*128 + q)*5 + t];
        momsh[t] = s;
    }
    __syncthreads();
    if (t < 64) {
        const float* W  = g ? p.W4 : p.W3;
        const float* gv = g ? p.b4g : p.b3g;
        const float* bv = g ? p.b4b : p.b3b;
        float Nr = (float)EN;
        float S0 = momsh[0], S1 = momsh[1], S00 = momsh[2], S11 = momsh[3], S01 = momsh[4];
        float w0 = W[t], w1 = W[64 + t];
        float m = (S0*w0 + S1*w1) / Nr;
        float E2 = (S00*w0*w0 + 2.0f*S01*w0*w1 + S11*w1*w1) / Nr;
        float var = E2 - m*m;
        float s = gv[t] * rsqrtf(var + EPS);
        st[t] = w0 * s; st[64 + t] = w1 * s; st[128 + t] = bv[t] - m*s;
    }
    __syncthreads();
    if (t < 128) {
        int h = t;
        const float* Wg = (seg == 0 ? p.Wga : (seg == 1 ? p.Wgp : p.Wgd)) + lay*320*H;
        float P = 0, Q = 0, Rr = 0;
        for (int cc = 0; cc < HE; cc++) {
            float w = Wg[(2*H + cc)*H + h];
            P += st[cc]*w; Q += st[64 + cc]*w; Rr += st[128 + cc]*w;
        }
        float* o = p.ws + OFF_PQR + ((g*3 + seg)*3 + lay)*384;
        o[h] = P; o[128 + h] = Q; o[256 + h] = Rr;
    }
}

// ---- fused GEMM (x->V->AB), 8-row tiles; float4 stage; rotate weight dbuf;
//      lay 0: +18 tail blocks run pqr, and node-BN applied on load ----
__global__ __launch_bounds__(256) void kf_gemm(KParams p, int lay) {
    int tid = threadIdx.x;
    if (blockIdx.x >= 808) {          // only launched with extra blocks at lay==0
        pqr_body(blockIdx.x - 808, tid, p);
        return;
    }
    __shared__ float xs[8*H];
    __shared__ float vs[8*H];
    __shared__ float scs[3*128], shs[3*128];
    int g = blockIdx.x / 404, tb = blockIdx.x % 404;
    int rowbase = tb * 8;
    float* ws = p.ws;
    if (lay == 0 && tid < 128) {
        int c = tid;
        #pragma unroll
        for (int seg = 0; seg < 3; seg++) {
            int lo = seg == 0 ? 0 : (seg == 1 ? 2 : 52);
            int hi = seg == 0 ? 2 : (seg == 1 ? 52 : 102);
            float s = 0, ss = 0;
            for (int q = lo; q < hi; q++) {
                s  += ws[NODE_PART + q*256 + c];
                ss += ws[NODE_PART + q*256 + 128 + c];
            }
            float cnt = seg == 0 ? 32.0f : 800.0f;
            float m = s / cnt, v = ss / cnt - m*m;
            const float* gp = seg == 0 ? p.b0g : (seg == 1 ? p.b1g : p.b2g);
            const float* bp = seg == 0 ? p.b0b : (seg == 1 ? p.b1b : p.b2b);
            float sc = gp[c] * rsqrtf(v + EPS);
            scs[seg*128 + c] = sc;
            shs[seg*128 + c] = bp[c] - m*sc;
        }
    }
    __syncthreads();
    // stage: 8 rows x 32 k-quads = 256 slots, one per thread
    {
        int r = tid >> 5, kq = tid & 31;
        int b, node; decode_vrow(rowbase + r, b, node);
        float4 val;
        if (lay == 0) {
            const float* x0 = ws + OFF_X0;
            int s3 = node < D ? 0 : (node < D + N2 ? 1 : 2);
            float4 xv = *(const float4*)&x0[(b*NA + node)*H + 4*kq];
            float4 sc = *(const float4*)&scs[s3*128 + 4*kq];
            float4 sh = *(const float4*)&shs[s3*128 + 4*kq];
            val.x = xv.x*sc.x + sh.x; val.y = xv.y*sc.y + sh.y;
            val.z = xv.z*sc.z + sh.z; val.w = xv.w*sc.w + sh.w;
        } else {
            val = combined_parts4(ws, g, b, node, kq);
        }
        *(float4*)&xs[r*H + 4*kq] = val;
    }
    __syncthreads();
    int seg = tb < 204 ? 0 : (tb < 304 ? 1 : 2);
    const float* W = (seg == 0 ? p.Wvla : (seg == 1 ? p.Wvlp : p.Wvld)) + lay*H*H;
    int col = tid & 127, half = tid >> 7;
    float acc[4] = {0,0,0,0};
    const float* Wp = W + col;
    float w0 = Wp[0], w1 = Wp[H], w2 = Wp[2*H], w3 = Wp[3*H];
    for (int k4 = 0; k4 < 32; k4++) {
        int kn = ((k4 + 1) & 31) * 4;
        const float* q = Wp + kn*H;
        float n0 = q[0], n1 = q[H], n2 = q[2*H], n3 = q[3*H];
        #pragma unroll
        for (int rr = 0; rr < 4; rr++) {
            float4 x4 = *(const float4*)&xs[(half + rr*2)*H + 4*k4];
            acc[rr] = fmaf(x4.w, w3, fmaf(x4.z, w2, fmaf(x4.y, w1, fmaf(x4.x, w0, acc[rr]))));
        }
        w0 = n0; w1 = n1; w2 = n2; w3 = n3;
    }
    float* V = ws + OFF_V + g*RV*H;
    #pragma unroll
    for (int rr = 0; rr < 4; rr++) {
        vs[(half + rr*2)*H + col] = acc[rr];
        V[(rowbase + half + rr*2)*H + col] = acc[rr];
    }
    __syncthreads();
    const float* Wg = (seg == 0 ? p.Wga : (seg == 1 ? p.Wgp : p.Wgd)) + lay*320*H;
    const float* wb = Wg + ((tid >> 7) * H) * H + (tid & 127);
    float a2[8];
    #pragma unroll
    for (int rr = 0; rr < 8; rr++) a2[rr] = 0.0f;
    float v0 = wb[0], v1 = wb[H], v2 = wb[2*H], v3 = wb[3*H];
    for (int k4 = 0; k4 < 32; k4++) {
        int kn = ((k4 + 1) & 31) * 4;
        const float* q = wb + kn*H;
        float n0 = q[0], n1 = q[H], n2 = q[2*H], n3 = q[3*H];
        #pragma unroll
        for (int rr = 0; rr < 8; rr++) {
            float4 x4 = *(const float4*)&vs[rr*H + 4*k4];
            a2[rr] = fmaf(x4.w, v3, fmaf(x4.z, v2, fmaf(x4.y, v1, fmaf(x4.x, v0, a2[rr]))));
        }
        v0 = n0; v1 = n1; v2 = n2; v3 = n3;
    }
    float* AB = ws + OFF_AB + g*RV*2*H;
    #pragma unroll
    for (int rr = 0; rr < 8; rr++) AB[(rowbase + rr)*256 + tid] = a2[rr];
}

// ---- attention v6 (r13): one j per wave, i-halved blocks, partial (a,l) outputs ----
// grid (8, 432): kx=XCD; y: ih = y&1, jq = (y>>1)&1, y3 = y>>2 in [0,108)
__global__ __launch_bounds__(256, 6) void kf_attn(KParams p, int lay) {
    __shared__ float2 Bs[TI*64];
    __shared__ float2 Vs[TI*64];
    __shared__ float2 se[4*52];
    __shared__ int    msk[52];
    int kx = blockIdx.x, y = blockIdx.y;
    int ih = y & 1, jq = (y >> 1) & 1, y3 = y >> 2;
    int ci = y3 / 27, r = y3 % 27;
    int combo = kx + 8*ci;
    int g = combo >> 4, b = combo & 15;
    int seg, jg, n, o, base;
    if (r < 13)      { seg = 0; jg = r;      n = NA; o = 0;      base = 0; }
    else if (r < 20) { seg = 1; jg = r - 13; n = N2; o = D;      base = R1; }
    else             { seg = 2; jg = r - 20; n = N2; o = D + N2; base = R1 + R2; }
    int j0 = jg*8 + jq*4;
    int tid = threadIdx.x;
    int c = tid & 63, wv = tid >> 6;
    int j = j0 + wv;
    bool jok = j < n;
    int nh0 = (n + 1) >> 1;
    int i0 = ih * nh0;
    int cnt = min(nh0, n - i0);

    float* ws = p.ws;
    const float* pqr = ws + OFF_PQR + ((g*3 + seg)*3 + lay)*384;
    float2 Pv = ((const float2*)pqr)[c];
    float2 Qv = ((const float2*)(pqr + 128))[c];
    float2 Rv = ((const float2*)(pqr + 256))[c];
    const float2* ea = (const float2*)(g ? p.ear : p.ead);
    const int* mask = g ? p.mask_r : p.mask_d;
    const float* V  = ws + OFF_V  + g*RV*H   + base*H;
    const float* AB = ws + OFF_AB + g*RV*2*H + base*2*H;

    if (tid < cnt) {
        int i = i0 + tid;
        int ibase = b*NAE + (o + i)*NA + o + j0;
        int bits = 0;
        #pragma unroll
        for (int jj = 0; jj < 4; jj++) {
            int valid = (j0 + jj < n) ? (mask[ibase + jj] != 0) : 0;
            bits |= valid << jj;
            se[jj*52 + tid] = valid ? ea[ibase + jj] : make_float2(0.f, 0.f);
        }
        msk[tid] = bits;
    }

    float Ax = 0.f, Ay = 0.f;
    if (jok) {
        float2 Aj = ((const float2*)&AB[(b*n + j)*256])[c];
        Ax = Aj.x + Rv.x; Ay = Aj.y + Rv.y;
    }
    float2 lsum = make_float2(0.f, 0.f), asum = make_float2(0.f, 0.f);

    for (int t0 = 0; t0 < cnt; t0 += TI) {
        int rows = min(TI, cnt - t0);
        __syncthreads();                   // stage visible / prev tile consumed
        for (int idx = tid; idx < rows*64; idx += 256) {
            int ir = idx >> 6, cc = idx & 63;
            int gi = b*n + i0 + t0 + ir;
            Bs[ir*64 + cc] = *(const float2*)&AB[gi*256 + 128 + 2*cc];
            Vs[ir*64 + cc] = *(const float2*)&V[gi*128 + 2*cc];
        }
        __syncthreads();
        if (jok) {
            for (int ir = 0; ir < rows; ir++) {
                int ii = t0 + ir;
                if (!((msk[ii] >> wv) & 1)) continue;   // wave-uniform skip
                float2 Bi = Bs[ir*64 + c];
                float2 Vi = Vs[ir*64 + c];
                float2 ev = se[wv*52 + ii];
                float tx = fmaf(ev.x, Pv.x, fmaf(ev.y, Qv.x, Ax + Bi.x));
                float ty = fmaf(ev.x, Pv.y, fmaf(ev.y, Qv.y, Ay + Bi.y));
                tx = fminf(fmaxf(tx, SLOPE*tx), 80.0f);
                ty = fminf(fmaxf(ty, SLOPE*ty), 80.0f);
                float px = __expf(tx), py = __expf(ty);
                lsum.x += px; lsum.y += py;
                asum.x = fmaf(px, Vi.x, asum.x);
                asum.y = fmaf(py, Vi.y, asum.y);
            }
        }
    }
    if (jok) {
        int rowW = (ih*2 + g)*RV + base + b*n + j;
        ((float2*)&ws[OFF_XA + rowW*H])[c] = asum;
        ((float2*)&ws[OFF_XL + rowW*H])[c] = lsum;
    }
}

// ---- fused feed-forward, 8-row tiles; float4 stage; rotate weight dbuf ----
__global__ __launch_bounds__(256) void kf_ff(KParams p) {
    __shared__ float xs[8*H];
    __shared__ float hs[8*H];
    int g = blockIdx.x / 204, tb = blockIdx.x % 204;
    int rowbase = tb * 8;
    int tid = threadIdx.x;
    float* ws = p.ws;
    {
        int r = tid >> 5, kq = tid & 31;
        int ridx = rowbase + r;
        int b = ridx / NA, node = ridx % NA;
        float4 val = combined_parts4(ws, g, b, node, kq);
        *(float4*)&xs[r*H + 4*kq] = val;
    }
    __syncthreads();
    int col = tid & 127, half = tid >> 7;
    float acc[4] = {0,0,0,0};
    const float* W1p = p.ffw1 + col;
    float w0 = W1p[0], w1 = W1p[H], w2 = W1p[2*H], w3 = W1p[3*H];
    for (int k4 = 0; k4 < 32; k4++) {
        int kn = ((k4 + 1) & 31) * 4;
        const float* q = W1p + kn*H;
        float n0 = q[0], n1 = q[H], n2 = q[2*H], n3 = q[3*H];
        #pragma unroll
        for (int rr = 0; rr < 4; rr++) {
            float4 x4 = *(const float4*)&xs[(half + rr*2)*H + 4*k4];
            acc[rr] = fmaf(x4.w, w3, fmaf(x4.z, w2, fmaf(x4.y, w1, fmaf(x4.x, w0, acc[rr]))));
        }
        w0 = n0; w1 = n1; w2 = n2; w3 = n3;
    }
    float b1 = p.ffb1[col];
    #pragma unroll
    for (int rr = 0; rr < 4; rr++) {
        float hv = acc[rr] + b1;
        hs[(half + rr*2)*H + col] = hv > 0.0f ? hv : 0.0f;
    }
    __syncthreads();
    #pragma unroll
    for (int rr = 0; rr < 4; rr++) acc[rr] = 0.0f;
    const float* W2p = p.ffw2 + col;
    w0 = W2p[0]; w1 = W2p[H]; w2 = W2p[2*H]; w3 = W2p[3*H];
    for (int k4 = 0; k4 < 32; k4++) {
        int kn = ((k4 + 1) & 31) * 4;
        const float* q = W2p + kn*H;
        float n0 = q[0], n1 = q[H], n2 = q[2*H], n3 = q[3*H];
        #pragma unroll
        for (int rr = 0; rr < 4; rr++) {
            float4 x4 = *(const float4*)&hs[(half + rr*2)*H + 4*k4];
            acc[rr] = fmaf(x4.w, w3, fmaf(x4.z, w2, fmaf(x4.y, w1, fmaf(x4.x, w0, acc[rr]))));
        }
        w0 = n0; w1 = n1; w2 = n2; w3 = n3;
    }
    float b2 = p.ffb2[col];
    float* Z = ws + OFF_Z + g*R1*H;
    float ls = 0, lss = 0;
    #pragma unroll
    for (int rr = 0; rr < 4; rr++) {
        int row = rowbase + half + rr*2;
        float z = acc[rr] + b2 + xs[(half + rr*2)*H + col];
        Z[row*H + col] = z;
        ls += z; lss += z*z;
    }
    atomicAdd(&ws[ACC_FF + g*256 + col], ls);
    atomicAdd(&ws[ACC_FF + g*256 + 128 + col], lss);
}

// ---- final BN + output ----
__global__ __launch_bounds__(256) void kf_f3(KParams p) {
    int e = blockIdx.x * 256 + threadIdx.x;
    if (e >= 2*R1*H) return;
    int g = e / (R1*H);
    int c = e & 127;
    float m = p.ws[ACC_FF + g*256 + c] / 1632.0f;
    float v = p.ws[ACC_FF + g*256 + 128 + c] / 1632.0f - m*m;
    float sc = p.bng[c] * rsqrtf(v + EPS);
    float sh = p.bnb[c] - m*sc;
    p.out[e] = p.ws[OFF_Z + e] * sc + sh;
}

extern "C" void kernel_launch(void* const* d_in, const int* in_sizes, int n_in,
                              void* d_out, int out_size, void* d_ws, size_t ws_size,
                              hipStream_t stream) {
    KParams p;
    p.x    = (const float*)d_in[0];
    p.dm   = (const float*)d_in[1];
    p.tw   = (const float*)d_in[2];
    p.ead  = (const float*)d_in[3];
    p.ear  = (const float*)d_in[4];
    p.W0   = (const float*)d_in[5];
    p.W1   = (const float*)d_in[6];
    p.W2   = (const float*)d_in[7];
    p.W3   = (const float*)d_in[8];
    p.W4   = (const float*)d_in[9];
    p.b0g  = (const float*)d_in[10];
    p.b0b  = (const float*)d_in[11];
    p.b1g  = (const float*)d_in[12];
    p.b1b  = (const float*)d_in[13];
    p.b2g  = (const float*)d_in[14];
    p.b2b  = (const float*)d_in[15];
    p.b3g  = (const float*)d_in[16];
    p.b3b  = (const float*)d_in[17];
    p.b4g  = (const float*)d_in[18];
    p.b4b  = (const float*)d_in[19];
    p.ffw1 = (const float*)d_in[20];
    p.ffb1 = (const float*)d_in[21];
    p.ffw2 = (const float*)d_in[22];
    p.ffb2 = (const float*)d_in[23];
    p.bng  = (const float*)d_in[24];
    p.bnb  = (const float*)d_in[25];
    p.Wvla = (const float*)d_in[26];
    p.Wvlp = (const float*)d_in[27];
    p.Wvld = (const float*)d_in[28];
    p.Wga  = (const float*)d_in[29];
    p.Wgp  = (const float*)d_in[30];
    p.Wgd  = (const float*)d_in[31];
    p.mask_d = (const int*)d_in[33];
    p.mask_r = (const int*)d_in[34];
    p.ws  = (float*)d_ws;
    p.out = (float*)d_out;

    kf_A<<<308, 256, 0, stream>>>(p);
    for (int lay = 0; lay < L; lay++) {
        kf_gemm<<<lay == 0 ? 826 : 808, 256, 0, stream>>>(p, lay);
        kf_attn<<<dim3(8, 432), 256, 0, stream>>>(p, lay);
    }
    kf_ff<<<408, 256, 0, stream>>>(p);
    kf_f3<<<1632, 256, 0, stream>>>(p);
}